// Round 19
// baseline (62.025 us; speedup 1.0000x reference)
//
#include <hip/hip_runtime.h>
#include <hip/hip_bf16.h>
#include <math.h>

#define NROWS 131072
#define NCODE 512
#define DIM 128
#define ESCALE 256.0f       // emb * 2^8 into fp8 (raw |e|~0.001 underflows e4m3)
#define DESCALE 0.0078125f  // 2/256: sv = e2 - 2*dot = e2 - DESCALE*acc

typedef long long llong;
typedef __attribute__((ext_vector_type(16))) float f32x16;

__device__ inline llong mk_ll(int lo, int hi) {
    return ((llong)(unsigned long long)(unsigned)hi << 32) | (unsigned)lo;
}

// Stuff the 9-bit code index into the low mantissa bits of the score (v_bfi).
// Perturbs sv by < ~1e-6; fp8 score error budget is ~5e-4. Min over keys ==
// min over scores; index rides inside the value through fmin trees & shuffles.
__device__ inline float kstuff(float sv, int code) {
    return __uint_as_float((__float_as_uint(sv) & 0xFFFFFE00u) | (unsigned)code);
}

// Fused prep: one block per 32-code M-tile.
//  - afp[(mt*4+q)*64 + lane]: fp8 A-fragments of emb*256 in lane order
//  - e2p[mt*32 + g*16 + r]:  ||e||^2 (fp32 exact) in D-fragment order
__global__ __launch_bounds__(256) void prep_pack8(const float* __restrict__ emb,
        int4* __restrict__ afp, float* __restrict__ e2p) {
    __shared__ float part[32][8];
    const int tid = threadIdx.x;
    const int mt = blockIdx.x;
    const int lane = tid & 63, q = tid >> 6;        // q in 0..3
    const int c5 = lane & 31, g = lane >> 5;
    const int code = mt * 32 + c5;
    const float* src = emb + (size_t)code * DIM;

    int w[4];
    float ss = 0.f;
    #pragma unroll
    for (int h = 0; h < 2; ++h) {
        int d0 = (2 * q + h) * 16 + g * 8;
        float4 v0 = *reinterpret_cast<const float4*>(src + d0);
        float4 v1 = *reinterpret_cast<const float4*>(src + d0 + 4);
        ss = fmaf(v0.x, v0.x, ss); ss = fmaf(v0.y, v0.y, ss);
        ss = fmaf(v0.z, v0.z, ss); ss = fmaf(v0.w, v0.w, ss);
        ss = fmaf(v1.x, v1.x, ss); ss = fmaf(v1.y, v1.y, ss);
        ss = fmaf(v1.z, v1.z, ss); ss = fmaf(v1.w, v1.w, ss);
        int lo = __builtin_amdgcn_cvt_pk_fp8_f32(v0.x * ESCALE, v0.y * ESCALE, 0, false);
        lo = __builtin_amdgcn_cvt_pk_fp8_f32(v0.z * ESCALE, v0.w * ESCALE, lo, true);
        int hi = __builtin_amdgcn_cvt_pk_fp8_f32(v1.x * ESCALE, v1.y * ESCALE, 0, false);
        hi = __builtin_amdgcn_cvt_pk_fp8_f32(v1.z * ESCALE, v1.w * ESCALE, hi, true);
        w[2 * h] = lo; w[2 * h + 1] = hi;
    }
    afp[(mt * 4 + q) * 64 + lane] = make_int4(w[0], w[1], w[2], w[3]);
    part[c5][q * 2 + g] = ss;
    __syncthreads();
    if (tid < 32) {
        float s = 0.f;
        #pragma unroll
        for (int j = 0; j < 8; ++j) s += part[tid][j];   // fixed order: deterministic
        int g2 = (tid >> 2) & 1;
        int r = (tid & 3) | ((tid >> 3) << 2);
        e2p[mt * 32 + g2 * 16 + r] = s;
    }
}

// Block = 8 waves x 256 rows; ENTIRE 64 KB fp8 codebook staged in LDS —
// removes the chip-wide contended L2 A-stream (the suspected scale-invariant
// ~43 µs binder across r12/r16/r17/r18). Wave = 32 rows x all 512 codes:
// A via conflict-free contiguous ds_read_b128; no cross-wave merges, no
// barriers after the staging one; gather indices broadcast via shfl.
__global__ __launch_bounds__(512, 2) void vq_argmin(
        const float* __restrict__ x, const float* __restrict__ emb,
        const int4* __restrict__ afp, const float* __restrict__ e2p,
        int* __restrict__ idxg,
        float* __restrict__ out0, float* __restrict__ out1, float* __restrict__ out2) {
    __shared__ unsigned char xs8[256][DIM];   // 32 KB fp8 rows, byte off ^= ((row&15)<<3)
    __shared__ int4 afp_lds[4096];            // 64 KB codebook A-fragments
    __shared__ float x2s[256];

    const int tid = threadIdx.x;
    const int lane = tid & 63, l31 = lane & 31, g = lane >> 5;
    const int wv = tid >> 6;                  // 0..7
    const long row0 = (long)blockIdx.x * 256;

    // ---- coalesced ingest: per it, each 32-lane group covers one full row ----
    {
        const float4* xg = reinterpret_cast<const float4*>(x + row0 * DIM);
        #pragma unroll
        for (int it = 0; it < 16; ++it) {
            int i = it * 512 + tid;
            float4 v = xg[i];
            int r = i >> 5, c = i & 31;
            float s = v.x * v.x + v.y * v.y + v.z * v.z + v.w * v.w;
            s += __shfl_xor(s, 1);  s += __shfl_xor(s, 2);
            s += __shfl_xor(s, 4);  s += __shfl_xor(s, 8);
            s += __shfl_xor(s, 16);
            if ((tid & 31) == 0) x2s[r] = s;
            int w = __builtin_amdgcn_cvt_pk_fp8_f32(v.x, v.y, 0, false);
            w = __builtin_amdgcn_cvt_pk_fp8_f32(v.z, v.w, w, true);
            int off = (c * 4) ^ ((r & 15) << 3);
            *reinterpret_cast<int*>(&xs8[r][off]) = w;
        }
    }
    // ---- stage codebook A-fragments: straight 64 KB copy, fully coalesced ----
    #pragma unroll
    for (int it = 0; it < 8; ++it) {
        int i = it * 512 + tid;
        afp_lds[i] = afp[i];
    }
    __syncthreads();

    const int rr = wv * 32 + l31;             // the row this lane owns

    // ---- B-fragments from LDS (8 x 8B, once per wave) ----
    #define RB(K) *reinterpret_cast<const llong*>(&xs8[rr][((K) * 16 + g * 8) ^ ((rr & 15) << 3)])
    const llong b0 = RB(0), b1 = RB(1), b2 = RB(2), b3 = RB(3);
    const llong b4 = RB(4), b5 = RB(5), b6 = RB(6), b7 = RB(7);
    #undef RB

    float m1 = 1e30f;                         // index-stuffed running min key

    // ---- 16 M-tiles (all 512 codes); A from LDS, 4 ds_read_b128 + 8 MFMA ----
    #pragma unroll 1
    for (int mt = 0; mt < 16; ++mt) {
        const int4* ap = afp_lds + mt * 256 + lane;
        int4 A0 = ap[0];
        int4 A1 = ap[64];
        int4 A2 = ap[128];
        int4 A3 = ap[192];
        f32x16 acc = {};
        acc = __builtin_amdgcn_mfma_f32_32x32x16_fp8_fp8(mk_ll(A0.x, A0.y), b0, acc, 0, 0, 0);
        acc = __builtin_amdgcn_mfma_f32_32x32x16_fp8_fp8(mk_ll(A0.z, A0.w), b1, acc, 0, 0, 0);
        acc = __builtin_amdgcn_mfma_f32_32x32x16_fp8_fp8(mk_ll(A1.x, A1.y), b2, acc, 0, 0, 0);
        acc = __builtin_amdgcn_mfma_f32_32x32x16_fp8_fp8(mk_ll(A1.z, A1.w), b3, acc, 0, 0, 0);
        acc = __builtin_amdgcn_mfma_f32_32x32x16_fp8_fp8(mk_ll(A2.x, A2.y), b4, acc, 0, 0, 0);
        acc = __builtin_amdgcn_mfma_f32_32x32x16_fp8_fp8(mk_ll(A2.z, A2.w), b5, acc, 0, 0, 0);
        acc = __builtin_amdgcn_mfma_f32_32x32x16_fp8_fp8(mk_ll(A3.x, A3.y), b6, acc, 0, 0, 0);
        acc = __builtin_amdgcn_mfma_f32_32x32x16_fp8_fp8(mk_ll(A3.z, A3.w), b7, acc, 0, 0, 0);

        const float4* ev = reinterpret_cast<const float4*>(e2p + mt * 32 + g * 16);
        const int base = mt * 32 + 4 * g;
        float4 ea = ev[0], eb = ev[1], ec = ev[2], ed = ev[3];
        float earr[16] = {ea.x, ea.y, ea.z, ea.w, eb.x, eb.y, eb.z, eb.w,
                          ec.x, ec.y, ec.z, ec.w, ed.x, ed.y, ed.z, ed.w};
        float k0[16];
        #pragma unroll
        for (int r = 0; r < 16; ++r) {
            int code = base + (r & 3) + 8 * (r >> 2);
            k0[r] = kstuff(earr[r] - DESCALE * acc[r], code);
        }
        #pragma unroll
        for (int s = 8; s > 0; s >>= 1)
            #pragma unroll
            for (int r = 0; r < s; ++r)
                k0[r] = fminf(k0[r], k0[r + s]);
        m1 = fminf(m1, k0[0]);
    }

    // g-half merge: after this, BOTH lanes (l, l+32) hold row rr's final key
    m1 = fminf(m1, __shfl_xor(m1, 32));
    const unsigned kb = __float_as_uint(m1);
    const int idx = (int)(kb & 0x1FFu);
    const float sv = __uint_as_float(kb & 0xFFFFFE00u);

    if (lane < 32) {
        long row = row0 + rr;
        idxg[row] = idx;
        float o = x2s[rr] + sv;   // ||x||^2 + (||e||^2 - 2 x.e); err ~1e-3 << 4.24
        out1[row] = o;
        out2[row] = o;
    }

    // ---- gather: wave writes its 32 rows, idx broadcast via shfl (no LDS) ----
    {
        const float4* e4 = reinterpret_cast<const float4*>(emb);
        float4* o4 = reinterpret_cast<float4*>(out0) + (row0 + wv * 32) * 32;
        #pragma unroll 4
        for (int rx = 0; rx < 32; rx += 2) {
            int c0 = __shfl(idx, rx);
            int c1 = __shfl(idx, rx + 1);
            int c = g ? c1 : c0;
            int r = rx + g;
            o4[r * 32 + l31] = e4[c * 32 + l31];
        }
    }
}

// Stage A: 64 blocks build LDS partial histograms (2048 rows each) — LDS
// atomics only, no global atomics anywhere.
__global__ __launch_bounds__(256) void hist_part(const int* __restrict__ idxg,
        int* __restrict__ partial) {
    __shared__ int h[NCODE];
    const int tid = threadIdx.x, b = blockIdx.x;
    h[tid] = 0; h[tid + 256] = 0;
    __syncthreads();
    const int4* i4 = reinterpret_cast<const int4*>(idxg + b * 2048);
    #pragma unroll
    for (int k = 0; k < 2; ++k) {
        int4 v = i4[k * 256 + tid];
        atomicAdd(&h[v.x], 1); atomicAdd(&h[v.y], 1);
        atomicAdd(&h[v.z], 1); atomicAdd(&h[v.w], 1);
    }
    __syncthreads();
    partial[b * NCODE + tid] = h[tid];
    partial[b * NCODE + 256 + tid] = h[tid + 256];
}

// Stage B: sum 64 partials per bin, entropy reduce.
__global__ void entropy_kernel(const int* __restrict__ partial,
        float* __restrict__ oent) {
    __shared__ float red[8];
    int tid = threadIdx.x;  // 512 threads
    int c = 0;
    #pragma unroll
    for (int b = 0; b < 64; ++b) c += partial[b * NCODE + tid];
    float p = (float)c * (1.0f / 131072.0f);
    float t = (p > 0.f) ? (-p * logf(p)) : 0.f;
    #pragma unroll
    for (int off = 32; off > 0; off >>= 1) t += __shfl_down(t, off);
    if ((tid & 63) == 0) red[tid >> 6] = t;
    __syncthreads();
    if (tid == 0) {
        float s = 0.f;
        #pragma unroll
        for (int i = 0; i < 8; ++i) s += red[i];
        *oent = s;
    }
}

extern "C" void kernel_launch(void* const* d_in, const int* in_sizes, int n_in,
                              void* d_out, int out_size, void* d_ws, size_t ws_size,
                              hipStream_t stream) {
    const float* x   = (const float*)d_in[0];
    const float* emb = (const float*)d_in[1];
    float* out  = (float*)d_out;
    float* out0 = out;
    float* out1 = out0 + (size_t)NROWS * DIM;
    float* out2 = out1 + NROWS;
    float* oent = out2 + NROWS;

    float* e2p = (float*)d_ws;                                    // 2 KB
    int4*  afp = (int4*)((char*)d_ws + 4096);                     // 64 KB
    int*   idxg = (int*)((char*)d_ws + 4096 + 65536);             // 512 KB
    int*   partial = (int*)((char*)d_ws + 4096 + 65536 + 524288); // 128 KB

    prep_pack8<<<16, 256, 0, stream>>>(emb, afp, e2p);
    vq_argmin<<<NROWS / 256, 512, 0, stream>>>(x, emb, afp, e2p, idxg, out0, out1, out2);
    hist_part<<<64, 256, 0, stream>>>(idxg, partial);
    entropy_kernel<<<1, NCODE, 0, stream>>>(partial, oent);
}